// Round 1
// baseline (771.937 us; speedup 1.0000x reference)
//
#include <hip/hip_runtime.h>
#include <stdint.h>

// ---------------------------------------------------------------------------
// aggregated_embedding: heap binary-tree aggregation, 11 levels.
// Per level: out = root + (elu(elu(x@WinT+b_in)@W1T+b1)@W2T+b2), x = [root,left,right]
// bf16 MFMA (16x16x32), fp32 accumulate, fp32 residual root from E.
// Block = 256 thr (4 waves) -> 64 rows x 256 cols, 3 GEMMs fused in-block.
// ws layout (needs ~67.5 MB):
//   [0)            Ebf   32064*256 bf16   (16,416,768 B)
//   [16,416,768)   Winbf 256*768  bf16    (393,216 B)
//   [16,809,984)   W1bf  256*256  bf16    (131,072 B)
//   [16,941,056)   W2bf  256*256  bf16    (131,072 B)
//   [17,072,128)   curA  64*1024*256 bf16 (33,554,432 B)
//   [50,626,560)   curB  64*512*256 bf16  (16,777,216 B)
// ---------------------------------------------------------------------------

typedef __attribute__((ext_vector_type(8))) short short8;   // 8 x bf16 frag
typedef __attribute__((ext_vector_type(4))) float f32x4;    // MFMA C/D

#define XS_STRIDE 264   // 256 + 8 bf16 pad: row stride 528B = 33*16 (b128-aligned), 2-way bank alias only
#define TOK_N 4095

__device__ __forceinline__ unsigned short f32_to_bf16(float f) {
    union { float f; unsigned u; } v; v.f = f;
    return (unsigned short)((v.u + 0x7fffu + ((v.u >> 16) & 1u)) >> 16);  // RNE
}

// ---- one-shot fp32 -> bf16 conversion of E and the three weight matrices ----
__global__ void convert_f32_bf16(const float* __restrict__ E,
                                 const float* __restrict__ Win,
                                 const float* __restrict__ W1,
                                 const float* __restrict__ W2,
                                 unsigned short* __restrict__ Ebf,
                                 unsigned short* __restrict__ Winbf,
                                 unsigned short* __restrict__ W1bf,
                                 unsigned short* __restrict__ W2bf) {
    const int nE = 32064 * 256, nWin = 256 * 768, nW = 256 * 256;
    const int total4 = (nE + nWin + 2 * nW) >> 2;
    for (int i = blockIdx.x * blockDim.x + threadIdx.x; i < total4;
         i += gridDim.x * blockDim.x) {
        int idx = i << 2;
        const float* src; unsigned short* dst; int off;
        if (idx < nE)                  { src = E;   dst = Ebf;   off = idx; }
        else if (idx < nE + nWin)      { src = Win; dst = Winbf; off = idx - nE; }
        else if (idx < nE + nWin + nW) { src = W1;  dst = W1bf;  off = idx - nE - nWin; }
        else                           { src = W2;  dst = W2bf;  off = idx - nE - nWin - nW; }
        float4 f = *(const float4*)(src + off);
        ushort4 o;
        o.x = f32_to_bf16(f.x); o.y = f32_to_bf16(f.y);
        o.z = f32_to_bf16(f.z); o.w = f32_to_bf16(f.w);
        *(ushort4*)(dst + off) = o;
    }
}

// ---- K=256 MFMA pass: A from LDS (rows), B direct from global weights ----
// A-frag: lane holds A[m=lane&15][k=quad*8+j]; B-frag: B[k=quad*8+j][n=lane&15]
// which for W stored row-major [n][k] is a contiguous 16B chunk of row n.
template<int WROW>
__device__ __forceinline__ void gemm_k256(const unsigned short* __restrict__ lds,
                                          const unsigned short* __restrict__ W,
                                          int kbase, int l15, int q, int n0,
                                          f32x4 acc[4][4]) {
#pragma unroll
    for (int k0 = 0; k0 < 256; k0 += 32) {
        short8 a[4], bb[4];
#pragma unroll
        for (int mt = 0; mt < 4; ++mt)
            a[mt] = *(const short8*)(lds + (mt * 16 + l15) * XS_STRIDE + k0 + q * 8);
#pragma unroll
        for (int nt = 0; nt < 4; ++nt)
            bb[nt] = *(const short8*)(W + (size_t)(n0 + nt * 16 + l15) * WROW + kbase + k0 + q * 8);
#pragma unroll
        for (int mt = 0; mt < 4; ++mt)
#pragma unroll
            for (int nt = 0; nt < 4; ++nt)
                acc[mt][nt] = __builtin_amdgcn_mfma_f32_16x16x32_bf16(
                    a[mt], bb[nt], acc[mt][nt], 0, 0, 0);
    }
}

__global__ __launch_bounds__(256, 2)
void tree_level(const int* __restrict__ tokens,
                const float* __restrict__ Ef,          // fp32 E (residual root)
                const unsigned short* __restrict__ Ebf,
                const unsigned short* __restrict__ Win,
                const unsigned short* __restrict__ W1,
                const unsigned short* __restrict__ W2,
                const float* __restrict__ b_in,
                const float* __restrict__ b1,
                const float* __restrict__ b2,
                const unsigned short* __restrict__ cur_in,
                unsigned short* __restrict__ cur_out,
                float* __restrict__ final_out,
                int L, int logL, int first, int last)
{
    __shared__ unsigned short Xs[64 * XS_STRIDE];  // gather buffer / H2 buffer
    __shared__ unsigned short Hs[64 * XS_STRIDE];  // H1 buffer

    const int tid  = threadIdx.x;
    const int lane = tid & 63;
    const int wid  = tid >> 6;
    const int l15  = lane & 15;
    const int q    = lane >> 4;
    const int n0   = wid * 64;       // wave's 64-col slice of the 256 cols
    const int blk  = blockIdx.x;     // 64-row block; grid.x == L

    f32x4 acc[4][4];
#pragma unroll
    for (int mt = 0; mt < 4; ++mt)
#pragma unroll
        for (int nt = 0; nt < 4; ++nt)
            acc[mt][nt] = (f32x4){0.f, 0.f, 0.f, 0.f};

    // ---------------- GEMM1: H1 = X @ Win^T, 3 gather phases of K=256 -------
    const int c = tid & 31;    // 16B chunk within a 512B row
    const int sub = tid >> 5;  // 8 rows gathered in parallel
    for (int p = 0; p < 3; ++p) {
#pragma unroll
        for (int it = 0; it < 8; ++it) {
            int r = it * 8 + sub;
            int g = blk * 64 + r;
            int b = g >> logL;
            int i = g - (b << logL);
            const unsigned short* src;
            if (p == 0) {                       // root embedding
                int tok = tokens[b * TOK_N + (L - 1) + i];
                src = Ebf + (size_t)tok * 256;
            } else if (first) {                 // leaves from E
                int tok = tokens[b * TOK_N + 2047 + 2 * i + (p - 1)];
                src = Ebf + (size_t)tok * 256;
            } else {                            // children from previous level
                src = cur_in + ((size_t)b * (2 * L) + 2 * i + (p - 1)) * 256;
            }
            *(short8*)(&Xs[r * XS_STRIDE + c * 8]) = *(const short8*)(src + c * 8);
        }
        __syncthreads();
        gemm_k256<768>(Xs, Win, p * 256, l15, q, n0, acc);
        __syncthreads();   // Xs reads done before next gather overwrites
    }

    // epilogue 1: Hs = bf16(elu(H1 + b_in));  D: row = q*4+reg, col = lane&15
    {
        float bv[4];
#pragma unroll
        for (int nt = 0; nt < 4; ++nt) bv[nt] = b_in[n0 + nt * 16 + l15];
#pragma unroll
        for (int mt = 0; mt < 4; ++mt)
#pragma unroll
            for (int nt = 0; nt < 4; ++nt)
#pragma unroll
                for (int r = 0; r < 4; ++r) {
                    float h = acc[mt][nt][r] + bv[nt];
                    h = h > 0.f ? h : (__expf(h) - 1.f);
                    Hs[(mt * 16 + q * 4 + r) * XS_STRIDE + n0 + nt * 16 + l15] =
                        f32_to_bf16(h);
                }
    }
    __syncthreads();

    // ---------------- GEMM2: H2 = elu(H1) @ W1^T ----------------------------
#pragma unroll
    for (int mt = 0; mt < 4; ++mt)
#pragma unroll
        for (int nt = 0; nt < 4; ++nt)
            acc[mt][nt] = (f32x4){0.f, 0.f, 0.f, 0.f};
    gemm_k256<256>(Hs, W1, 0, l15, q, n0, acc);

    // epilogue 2: Xs = bf16(elu(H2 + b1))   (Xs free since GEMM1 finished)
    {
        float bv[4];
#pragma unroll
        for (int nt = 0; nt < 4; ++nt) bv[nt] = b1[n0 + nt * 16 + l15];
#pragma unroll
        for (int mt = 0; mt < 4; ++mt)
#pragma unroll
            for (int nt = 0; nt < 4; ++nt)
#pragma unroll
                for (int r = 0; r < 4; ++r) {
                    float h = acc[mt][nt][r] + bv[nt];
                    h = h > 0.f ? h : (__expf(h) - 1.f);
                    Xs[(mt * 16 + q * 4 + r) * XS_STRIDE + n0 + nt * 16 + l15] =
                        f32_to_bf16(h);
                }
    }
    __syncthreads();

    // ---------------- GEMM3: H3 = elu(H2) @ W2^T ----------------------------
#pragma unroll
    for (int mt = 0; mt < 4; ++mt)
#pragma unroll
        for (int nt = 0; nt < 4; ++nt)
            acc[mt][nt] = (f32x4){0.f, 0.f, 0.f, 0.f};
    gemm_k256<256>(Xs, W2, 0, l15, q, n0, acc);

    // epilogue 3: out = root(fp32) + H3 + b2  (NO elu on the last layer)
    {
        float bv[4];
#pragma unroll
        for (int nt = 0; nt < 4; ++nt) bv[nt] = b2[n0 + nt * 16 + l15];
#pragma unroll
        for (int mt = 0; mt < 4; ++mt)
#pragma unroll
            for (int r = 0; r < 4; ++r) {
                int row = mt * 16 + q * 4 + r;
                int g = blk * 64 + row;
                int b = g >> logL;
                int i = g - (b << logL);
                int tok = tokens[b * TOK_N + (L - 1) + i];
                const float* er = Ef + (size_t)tok * 256;
#pragma unroll
                for (int nt = 0; nt < 4; ++nt) {
                    int col = n0 + nt * 16 + l15;
                    float o = er[col] + acc[mt][nt][r] + bv[nt];
                    if (last) final_out[(size_t)g * 256 + col] = o;
                    else      cur_out[(size_t)g * 256 + col] = f32_to_bf16(o);
                }
            }
    }
}

extern "C" void kernel_launch(void* const* d_in, const int* in_sizes, int n_in,
                              void* d_out, int out_size, void* d_ws, size_t ws_size,
                              hipStream_t stream) {
    const int*   tokens = (const int*)  d_in[0];
    const float* E      = (const float*)d_in[1];
    const float* W_in   = (const float*)d_in[2];
    const float* b_in   = (const float*)d_in[3];
    const float* W1     = (const float*)d_in[4];
    const float* b1     = (const float*)d_in[5];
    const float* W2     = (const float*)d_in[6];
    const float* b2     = (const float*)d_in[7];
    float* out = (float*)d_out;
    char* ws = (char*)d_ws;

    unsigned short* Ebf   = (unsigned short*)(ws);
    unsigned short* Winbf = (unsigned short*)(ws + 16416768);
    unsigned short* W1bf  = (unsigned short*)(ws + 16809984);
    unsigned short* W2bf  = (unsigned short*)(ws + 16941056);
    unsigned short* curA  = (unsigned short*)(ws + 17072128);
    unsigned short* curB  = (unsigned short*)(ws + 50626560);

    convert_f32_bf16<<<1024, 256, 0, stream>>>(E, W_in, W1, W2,
                                               Ebf, Winbf, W1bf, W2bf);

    const unsigned short* cin = curA;   // unused at first level
    unsigned short* cout = curA;
    int first = 1;
    for (int L = 1024; L >= 1; L >>= 1) {
        int logL = 31 - __builtin_clz((unsigned)L);
        int last = (L == 1);
        tree_level<<<dim3(L), dim3(256), 0, stream>>>(
            tokens, E, Ebf, Winbf, W1bf, W2bf, b_in, b1, b2,
            cin, last ? nullptr : cout, last ? out : nullptr,
            L, logL, first, last);
        cin = cout;
        cout = (cout == curA) ? curB : curA;
        first = 0;
    }
}

// Round 2
// 530.742 us; speedup vs baseline: 1.4544x; 1.4544x over previous
//
#include <hip/hip_runtime.h>
#include <stdint.h>

// ---------------------------------------------------------------------------
// aggregated_embedding: heap binary-tree aggregation, 11 levels.
// Per level: out = root + (elu(elu(x@WinT+b_in)@W1T+b1)@W2T+b2), x=[root,left,right]
// bf16 MFMA 16x16x32, fp32 accumulate. Round 2:
//  - single in-place LDS buffer (33.8KB) -> 4 blocks/CU (was 2)
//  - rolling 2-kstep B preload from L2 (overlap MFMA with weight-load latency)
//  - gather prefetch for next phase + residual root issued during MFMA passes
//  - residual root re-gathered as bf16 (intermediate levels store bf16 anyway)
//  - MT template: rows/block = MT*16, MT=4/2/1 to keep grid >= ~512 blocks
// ws layout:
//   [0)            Ebf   32064*256 bf16
//   [16,416,768)   Winbf 256*768  bf16   (row-major [n][k] = MFMA B-frag order)
//   [16,809,984)   W1bf  256*256  bf16
//   [16,941,056)   W2bf  256*256  bf16
//   [17,072,128)   curA  64*1024*256 bf16
//   [50,626,560)   curB  64*512*256 bf16
// ---------------------------------------------------------------------------

typedef __attribute__((ext_vector_type(8))) short short8;   // 8 x bf16 frag
typedef __attribute__((ext_vector_type(4))) float f32x4;    // MFMA C/D

#define XS_STRIDE 264   // 256+8 pad: row stride 528B, b128-aligned, 2-way bank alias (free)
#define TOK_N 4095

__device__ __forceinline__ unsigned short f32_to_bf16(float f) {
    union { float f; unsigned u; } v; v.f = f;
    return (unsigned short)((v.u + 0x7fffu + ((v.u >> 16) & 1u)) >> 16);  // RNE
}
__device__ __forceinline__ float bf16_to_f32(unsigned short u) {
    union { unsigned u; float f; } v; v.u = ((unsigned)u) << 16; return v.f;
}

__global__ void convert_f32_bf16(const float* __restrict__ E,
                                 const float* __restrict__ Win,
                                 const float* __restrict__ W1,
                                 const float* __restrict__ W2,
                                 unsigned short* __restrict__ Ebf,
                                 unsigned short* __restrict__ Winbf,
                                 unsigned short* __restrict__ W1bf,
                                 unsigned short* __restrict__ W2bf) {
    const int nE = 32064 * 256, nWin = 256 * 768, nW = 256 * 256;
    const int total4 = (nE + nWin + 2 * nW) >> 2;
    for (int i = blockIdx.x * blockDim.x + threadIdx.x; i < total4;
         i += gridDim.x * blockDim.x) {
        int idx = i << 2;
        const float* src; unsigned short* dst; int off;
        if (idx < nE)                  { src = E;   dst = Ebf;   off = idx; }
        else if (idx < nE + nWin)      { src = Win; dst = Winbf; off = idx - nE; }
        else if (idx < nE + nWin + nW) { src = W1;  dst = W1bf;  off = idx - nE - nWin; }
        else                           { src = W2;  dst = W2bf;  off = idx - nE - nWin - nW; }
        float4 f = *(const float4*)(src + off);
        ushort4 o;
        o.x = f32_to_bf16(f.x); o.y = f32_to_bf16(f.y);
        o.z = f32_to_bf16(f.z); o.w = f32_to_bf16(f.w);
        *(ushort4*)(dst + off) = o;
    }
}

// ---------------------------------------------------------------------------
// tree_level<MT>: block = 256 thr (4 waves), R = MT*16 rows x 256 cols.
// Wave owns 64-col slice (n0), MT x 4 grid of 16x16 MFMA tiles.
// A-frag: lane holds A[m=lane&15][k=quad*8+j]; B-frag: W row-major 16B chunk.
// ---------------------------------------------------------------------------
template<int MT>
__global__ __launch_bounds__(256, 4)
void tree_level(const int* __restrict__ tokens,
                const unsigned short* __restrict__ Ebf,
                const unsigned short* __restrict__ Win,
                const unsigned short* __restrict__ W1,
                const unsigned short* __restrict__ W2,
                const float* __restrict__ b_in,
                const float* __restrict__ b1,
                const float* __restrict__ b2,
                const unsigned short* __restrict__ cur_in,
                unsigned short* __restrict__ cur_out,
                float* __restrict__ final_out,
                int L, int logL, int first, int last)
{
    constexpr int R = MT * 16;
    constexpr int GITER = R / 8;          // 16B-chunk gather iters per thread
    __shared__ unsigned short Xs[R * XS_STRIDE];

    const int tid  = threadIdx.x;
    const int lane = tid & 63;
    const int wid  = tid >> 6;
    const int l15  = lane & 15;
    const int q    = lane >> 4;
    const int n0   = wid * 64;
    const int blk  = blockIdx.x;
    const int c    = tid & 31;            // 16B chunk within 512B row
    const int sub  = tid >> 5;            // 8 rows gathered in parallel

    // gather source for (phase p, local row r)
    auto gsrc = [&](int p, int r) -> const unsigned short* {
        int g = blk * R + r;
        int b = g >> logL;
        int i = g - (b << logL);
        if (p == 0) {
            int tok = tokens[b * TOK_N + (L - 1) + i];
            return Ebf + (size_t)tok * 256;
        } else if (first) {
            int tok = tokens[b * TOK_N + 2047 + 2 * i + (p - 1)];
            return Ebf + (size_t)tok * 256;
        } else {
            return cur_in + ((size_t)b * (2 * L) + 2 * i + (p - 1)) * 256;
        }
    };

    short8 g[GITER];

    // ---- phase-0 gather (root) ------------------------------------------
#pragma unroll
    for (int it = 0; it < GITER; ++it)
        g[it] = *(const short8*)(gsrc(0, it * 8 + sub) + c * 8);
#pragma unroll
    for (int it = 0; it < GITER; ++it)
        *(short8*)(&Xs[(it * 8 + sub) * XS_STRIDE + c * 8]) = g[it];
    __syncthreads();

    f32x4 acc[MT][4];
    float bv[4];
#pragma unroll
    for (int nt = 0; nt < 4; ++nt) bv[nt] = b_in[n0 + nt * 16 + l15];
#pragma unroll
    for (int mt = 0; mt < MT; ++mt)
#pragma unroll
        for (int nt = 0; nt < 4; ++nt)
            acc[mt][nt] = (f32x4){bv[nt], bv[nt], bv[nt], bv[nt]};

    // ---- GEMM1: 3 phases of K=256 against Win (row stride 768) ----------
    const unsigned short* wbase = Win + q * 8 + (size_t)(n0 + l15) * 768;
    for (int p = 0; p < 3; ++p) {
        const int kbase = p * 256;
        short8 bb[2][4];                              // rolling 2-kstep preload
#pragma unroll
        for (int k = 0; k < 2; ++k)
#pragma unroll
            for (int nt = 0; nt < 4; ++nt)
                bb[k][nt] = *(const short8*)(wbase + (size_t)(nt * 16) * 768 + kbase + k * 32);
        if (p < 2) {                                  // prefetch next gather
#pragma unroll
            for (int it = 0; it < GITER; ++it)
                g[it] = *(const short8*)(gsrc(p + 1, it * 8 + sub) + c * 8);
        }
#pragma unroll
        for (int k = 0; k < 8; ++k) {
            short8 a[MT];
#pragma unroll
            for (int mt = 0; mt < MT; ++mt)
                a[mt] = *(const short8*)(&Xs[(mt * 16 + l15) * XS_STRIDE + k * 32 + q * 8]);
#pragma unroll
            for (int mt = 0; mt < MT; ++mt)
#pragma unroll
                for (int nt = 0; nt < 4; ++nt)
                    acc[mt][nt] = __builtin_amdgcn_mfma_f32_16x16x32_bf16(
                        a[mt], bb[k & 1][nt], acc[mt][nt], 0, 0, 0);
            if (k + 2 < 8) {
#pragma unroll
                for (int nt = 0; nt < 4; ++nt)
                    bb[k & 1][nt] = *(const short8*)(wbase + (size_t)(nt * 16) * 768 + kbase + (k + 2) * 32);
            }
        }
        __syncthreads();                               // all waves done reading Xs
        if (p < 2) {
#pragma unroll
            for (int it = 0; it < GITER; ++it)
                *(short8*)(&Xs[(it * 8 + sub) * XS_STRIDE + c * 8]) = g[it];
            __syncthreads();
        }
    }

    // ---- epilogue 1: Xs = bf16(elu(H1)) in place ------------------------
#pragma unroll
    for (int mt = 0; mt < MT; ++mt)
#pragma unroll
        for (int nt = 0; nt < 4; ++nt)
#pragma unroll
            for (int r = 0; r < 4; ++r) {
                float h = acc[mt][nt][r];
                h = h > 0.f ? h : (__expf(h) - 1.f);
                Xs[(mt * 16 + q * 4 + r) * XS_STRIDE + n0 + nt * 16 + l15] = f32_to_bf16(h);
            }
    __syncthreads();

    // ---- GEMM2: H2 = elu(H1) @ W1^T  (+ root re-gather prefetch) --------
#pragma unroll
    for (int nt = 0; nt < 4; ++nt) bv[nt] = b1[n0 + nt * 16 + l15];
#pragma unroll
    for (int mt = 0; mt < MT; ++mt)
#pragma unroll
        for (int nt = 0; nt < 4; ++nt)
            acc[mt][nt] = (f32x4){bv[nt], bv[nt], bv[nt], bv[nt]};
    {
        const unsigned short* w1base = W1 + q * 8 + (size_t)(n0 + l15) * 256;
        short8 bb[2][4];
#pragma unroll
        for (int k = 0; k < 2; ++k)
#pragma unroll
            for (int nt = 0; nt < 4; ++nt)
                bb[k][nt] = *(const short8*)(w1base + (size_t)(nt * 16) * 256 + k * 32);
        // residual root (bf16) re-gather: issued here, consumed after GEMM3
#pragma unroll
        for (int it = 0; it < GITER; ++it)
            g[it] = *(const short8*)(gsrc(0, it * 8 + sub) + c * 8);
#pragma unroll
        for (int k = 0; k < 8; ++k) {
            short8 a[MT];
#pragma unroll
            for (int mt = 0; mt < MT; ++mt)
                a[mt] = *(const short8*)(&Xs[(mt * 16 + l15) * XS_STRIDE + k * 32 + q * 8]);
#pragma unroll
            for (int mt = 0; mt < MT; ++mt)
#pragma unroll
                for (int nt = 0; nt < 4; ++nt)
                    acc[mt][nt] = __builtin_amdgcn_mfma_f32_16x16x32_bf16(
                        a[mt], bb[k & 1][nt], acc[mt][nt], 0, 0, 0);
            if (k + 2 < 8) {
#pragma unroll
                for (int nt = 0; nt < 4; ++nt)
                    bb[k & 1][nt] = *(const short8*)(w1base + (size_t)(nt * 16) * 256 + (k + 2) * 32);
            }
        }
    }
    __syncthreads();

    // ---- epilogue 2: Xs = bf16(elu(H2)) in place ------------------------
#pragma unroll
    for (int mt = 0; mt < MT; ++mt)
#pragma unroll
        for (int nt = 0; nt < 4; ++nt)
#pragma unroll
            for (int r = 0; r < 4; ++r) {
                float h = acc[mt][nt][r];
                h = h > 0.f ? h : (__expf(h) - 1.f);
                Xs[(mt * 16 + q * 4 + r) * XS_STRIDE + n0 + nt * 16 + l15] = f32_to_bf16(h);
            }
    __syncthreads();

    // ---- GEMM3: H3 = elu(H2) @ W2^T -------------------------------------
#pragma unroll
    for (int nt = 0; nt < 4; ++nt) bv[nt] = b2[n0 + nt * 16 + l15];
#pragma unroll
    for (int mt = 0; mt < MT; ++mt)
#pragma unroll
        for (int nt = 0; nt < 4; ++nt)
            acc[mt][nt] = (f32x4){bv[nt], bv[nt], bv[nt], bv[nt]};
    {
        const unsigned short* w2base = W2 + q * 8 + (size_t)(n0 + l15) * 256;
        short8 bb[2][4];
#pragma unroll
        for (int k = 0; k < 2; ++k)
#pragma unroll
            for (int nt = 0; nt < 4; ++nt)
                bb[k][nt] = *(const short8*)(w2base + (size_t)(nt * 16) * 256 + k * 32);
#pragma unroll
        for (int k = 0; k < 8; ++k) {
            short8 a[MT];
#pragma unroll
            for (int mt = 0; mt < MT; ++mt)
                a[mt] = *(const short8*)(&Xs[(mt * 16 + l15) * XS_STRIDE + k * 32 + q * 8]);
#pragma unroll
            for (int mt = 0; mt < MT; ++mt)
#pragma unroll
                for (int nt = 0; nt < 4; ++nt)
                    acc[mt][nt] = __builtin_amdgcn_mfma_f32_16x16x32_bf16(
                        a[mt], bb[k & 1][nt], acc[mt][nt], 0, 0, 0);
            if (k + 2 < 8) {
#pragma unroll
                for (int nt = 0; nt < 4; ++nt)
                    bb[k & 1][nt] = *(const short8*)(w2base + (size_t)(nt * 16) * 256 + (k + 2) * 32);
            }
        }
    }
    __syncthreads();
    // park the root rows (bf16) in Xs for transposed access by the epilogue
#pragma unroll
    for (int it = 0; it < GITER; ++it)
        *(short8*)(&Xs[(it * 8 + sub) * XS_STRIDE + c * 8]) = g[it];
    __syncthreads();

    // ---- epilogue 3: out = root + H3 (+b2 already in acc), no elu -------
#pragma unroll
    for (int mt = 0; mt < MT; ++mt)
#pragma unroll
        for (int r = 0; r < 4; ++r) {
            int row = mt * 16 + q * 4 + r;
            int gg  = blk * R + row;
#pragma unroll
            for (int nt = 0; nt < 4; ++nt) {
                int col = n0 + nt * 16 + l15;
                float o = acc[mt][nt][r] + bf16_to_f32(Xs[row * XS_STRIDE + col]);
                if (last) final_out[(size_t)gg * 256 + col] = o;
                else      cur_out[(size_t)gg * 256 + col] = f32_to_bf16(o);
            }
        }
}

extern "C" void kernel_launch(void* const* d_in, const int* in_sizes, int n_in,
                              void* d_out, int out_size, void* d_ws, size_t ws_size,
                              hipStream_t stream) {
    const int*   tokens = (const int*)  d_in[0];
    const float* E      = (const float*)d_in[1];
    const float* W_in   = (const float*)d_in[2];
    const float* b_in   = (const float*)d_in[3];
    const float* W1     = (const float*)d_in[4];
    const float* b1     = (const float*)d_in[5];
    const float* W2     = (const float*)d_in[6];
    const float* b2     = (const float*)d_in[7];
    float* out = (float*)d_out;
    char* ws = (char*)d_ws;

    unsigned short* Ebf   = (unsigned short*)(ws);
    unsigned short* Winbf = (unsigned short*)(ws + 16416768);
    unsigned short* W1bf  = (unsigned short*)(ws + 16809984);
    unsigned short* W2bf  = (unsigned short*)(ws + 16941056);
    unsigned short* curA  = (unsigned short*)(ws + 17072128);
    unsigned short* curB  = (unsigned short*)(ws + 50626560);

    convert_f32_bf16<<<1024, 256, 0, stream>>>(E, W_in, W1, W2,
                                               Ebf, Winbf, W1bf, W2bf);

    const unsigned short* cin = curA;
    unsigned short* cout = curA;
    int first = 1;
    for (int L = 1024; L >= 1; L >>= 1) {
        int logL = 31 - __builtin_clz((unsigned)L);
        int last = (L == 1);
        int MTs = (L >= 512) ? 4 : (L == 256 ? 2 : 1);
        int blocks = (64 * L) / (16 * MTs);
        if (MTs == 4)
            tree_level<4><<<dim3(blocks), dim3(256), 0, stream>>>(
                tokens, Ebf, Winbf, W1bf, W2bf, b_in, b1, b2,
                cin, last ? nullptr : cout, last ? out : nullptr, L, logL, first, last);
        else if (MTs == 2)
            tree_level<2><<<dim3(blocks), dim3(256), 0, stream>>>(
                tokens, Ebf, Winbf, W1bf, W2bf, b_in, b1, b2,
                cin, last ? nullptr : cout, last ? out : nullptr, L, logL, first, last);
        else
            tree_level<1><<<dim3(blocks), dim3(256), 0, stream>>>(
                tokens, Ebf, Winbf, W1bf, W2bf, b_in, b1, b2,
                cin, last ? nullptr : cout, last ? out : nullptr, L, logL, first, last);
        cin = cout;
        cout = (cout == curA) ? curB : curA;
        first = 0;
    }
}